// Round 19
// baseline (317.346 us; speedup 1.0000x reference)
//
#include <hip/hip_runtime.h>
#include <math.h>
#include <stdint.h>

#define N_NODES 10000
#define N_EDGES 160000
#define F 128
#define NB 8
#define HR 64
#define NSPEC 10
#define PI_F 3.14159265358979323846f
#define NPAD 10160
#define NT_MAX 635
#define ETILES 2500

typedef unsigned short ushort_t;
typedef __attribute__((ext_vector_type(8))) short short8;
typedef __attribute__((ext_vector_type(4))) float f32x4;

__device__ __forceinline__ float silu_f(float x){ return x / (1.f + expf(-x)); }
__device__ __forceinline__ float bfu(ushort_t u) {
    union { unsigned int i; float f; } v; v.i = ((unsigned int)u) << 16; return v.f;
}
__device__ __forceinline__ ushort_t f2bf(float f) {
    union { float f; unsigned int i; } v; v.f = f;
    unsigned int x = v.i;
    unsigned int r = (x + 0x7fffu + ((x >> 16) & 1u)) >> 16;
    return (ushort_t)r;
}
__device__ __forceinline__ short8 pack8(const float* p) {
    short8 r;
    #pragma unroll
    for (int i = 0; i < 8; ++i) r[i] = (short)f2bf(p[i]);
    return r;
}

// ---- 1: zero counters + aggF + convert weights ----
__global__ __launch_bounds__(256) void k_conv_zero(
    const float* __restrict__ linW, const float* __restrict__ scW, const float* __restrict__ rW2,
    ushort_t* __restrict__ WBlin0, ushort_t* __restrict__ WBsc0, ushort_t* __restrict__ W2T0,
    int* __restrict__ zero_base, float* __restrict__ aggF)
{
    const int gtid = blockIdx.x*256 + threadIdx.x;
    const int GRID = 1984*256;
    for (int i = gtid; i < 2*N_NODES + 32; i += GRID) zero_base[i] = 0;
    for (int i = gtid; i < NPAD*128; i += GRID) aggF[i] = 0.f;
    const int LINTOT = 2*NSPEC*16384;
    const int SCTOT  = NSPEC*16384;
    int i = gtid;
    if (i < LINTOT) {
        int mat = i >> 14;
        int r = i & 16383;
        int fo = r >> 7, fi = r & 127;
        WBlin0[(size_t)mat*16384 + fo*128 + fi] =
            f2bf(linW[((size_t)mat*4 + 0)*16384 + fi*128 + fo]);
    } else if (i < LINTOT + SCTOT) {
        int t2 = i - LINTOT;
        int sp = t2 >> 14;
        int r = t2 & 16383;
        int fo = r >> 7, fi = r & 127;
        WBsc0[(size_t)sp*16384 + fo*128 + fi] =
            f2bf(scW[((size_t)(NSPEC + sp)*4 + 0)*16384 + fi*128 + fo]);
    } else if (i < LINTOT + SCTOT + 2*128*64) {
        int t2 = i - LINTOT - SCTOT;
        int l = t2 >> 13; int r = t2 & 8191; int f = r >> 6; int k = r & 63;
        W2T0[t2] = f2bf(rW2[(size_t)l*HR*512 + (size_t)k*512 + 4*f]);
    }
}

// ---- 2: both histograms (raw ids) ----
__global__ void k_hist(const int* __restrict__ spec, const int* __restrict__ recv,
                       int* __restrict__ scnt, int* __restrict__ counts)
{
    int i = blockIdx.x*256 + threadIdx.x;
    if (i < N_EDGES) atomicAdd(&counts[recv[i]], 1);
    if (i < N_NODES) atomicAdd(&scnt[spec[i]], 1);
}

// ---- 3: sort fill with per-block local species scan; block 0 publishes sptr/psptr ----
__global__ __launch_bounds__(256) void k_sfill(
    const int* __restrict__ spec, const int* __restrict__ scnt,
    int* __restrict__ sptr, int* __restrict__ psptr,
    int* __restrict__ scur, int* __restrict__ perm,
    int* __restrict__ inv, int* __restrict__ specS, int* __restrict__ pn)
{
    __shared__ int sptrL[NSPEC+1], psptrL[NSPEC+1];
    const int t = threadIdx.x;
    if (t == 0) {
        int acc = 0, pacc = 0;
        for (int s = 0; s < NSPEC; ++s) {
            sptrL[s] = acc; psptrL[s] = pacc;
            acc += scnt[s];
            pacc += ((scnt[s] + 15) >> 4) << 4;
        }
        sptrL[NSPEC] = acc; psptrL[NSPEC] = pacc;
        if (blockIdx.x == 0) {
            for (int s = 0; s <= NSPEC; ++s) { sptr[s] = sptrL[s]; psptr[s] = psptrL[s]; }
        }
    }
    __syncthreads();
    int n = blockIdx.x*256 + t;
    if (n >= N_NODES) return;
    int s = spec[n];
    int pos = sptrL[s] + atomicAdd(&scur[s], 1);
    perm[pos] = n; inv[n] = pos; specS[pos] = s;
    pn[pos] = psptrL[s] + (pos - sptrL[s]);
}

// ---- 4: row_ptr scan (block 0) + fB0 init (other blocks) ----
__global__ __launch_bounds__(256) void k_scan_init(
    const int* __restrict__ counts, const int* __restrict__ perm, int* __restrict__ row_ptr,
    const int* __restrict__ specS, const int* __restrict__ pn,
    const float* __restrict__ embW, ushort_t* __restrict__ fB0)
{
    const int t = threadIdx.x;
    if (blockIdx.x == 0) {
        __shared__ int ps[256];
        int loc[40];
        int sum = 0;
        int base = t * 40;
        #pragma unroll
        for (int j = 0; j < 40; ++j) {
            int idx = base + j;
            int c = (idx < N_NODES) ? counts[perm[idx]] : 0;
            loc[j] = c; sum += c;
        }
        ps[t] = sum;
        __syncthreads();
        for (int off = 1; off < 256; off <<= 1) {
            int v = (t >= off) ? ps[t-off] : 0;
            __syncthreads();
            ps[t] += v;
            __syncthreads();
        }
        int ex = ps[t] - sum;
        #pragma unroll
        for (int j = 0; j < 40; ++j) {
            int idx = base + j;
            if (idx < N_NODES) row_ptr[idx] = ex;
            ex += loc[j];
        }
        if (t == 255) row_ptr[N_NODES] = ex;
    } else {
        int i = (blockIdx.x - 1)*256 + t;
        if (i < N_NODES*F) {
            int n = i >> 7, f = i & 127;
            fB0[(size_t)pn[n]*128 + f] = f2bf(embW[specS[n]*F + f]);
        }
    }
}

// ---- 5: CSR fill + basis + sender/receiver rows ----
__global__ void k_fill_pre(const int* __restrict__ recv, const int* __restrict__ senders,
                           const int* __restrict__ inv, const int* __restrict__ pn,
                           const int* __restrict__ row_ptr, int* __restrict__ cursor,
                           const float* __restrict__ vec,
                           float* __restrict__ basis_pos, int* __restrict__ sndrow,
                           int* __restrict__ rcvrow)
{
    int e = blockIdx.x*256 + threadIdx.x;
    if (e >= N_EDGES) return;
    int r = inv[recv[e]];
    int q = row_ptr[r] + atomicAdd(&cursor[r], 1);
    sndrow[q] = pn[inv[senders[e]]];
    rcvrow[q] = pn[r];
    float x = vec[e*3+0], y = vec[e*3+1], z = vec[e*3+2];
    float rr = sqrtf(x*x + y*y + z*z);
    rr = fmaxf(rr, 1e-9f);
    float rc = fminf(rr, 5.0f);
    float cut = 0.5f * (cosf(PI_F * rc * 0.2f) + 1.f);
    float pref = sqrtf(0.4f) * cut / rr;
    float B[8];
    #pragma unroll
    for (int k = 1; k <= 8; ++k) B[k-1] = pref * sinf(PI_F * 0.2f * (float)k * rr);
    float4* dst = (float4*)(basis_pos + (size_t)q*8);
    dst[0] = make_float4(B[0], B[1], B[2], B[3]);
    dst[1] = make_float4(B[4], B[5], B[6], B[7]);
}

// ---- 6: fused radial MLP + aggregation for one layer: aggF[row][f] += scal*rw ----
// 2500 blocks x 64 positions; rw lives only in LDS; CSR-run partial sums -> f32 atomics
__global__ __launch_bounds__(256) void k_rwagg(
    const int layer,
    const float* __restrict__ basis_pos,
    const float* __restrict__ rW1,
    const float* __restrict__ rb1,
    const ushort_t* __restrict__ W2T0,
    const int* __restrict__ sndrow,
    const int* __restrict__ rcvrow,
    const ushort_t* __restrict__ fB_in,
    float* __restrict__ aggF)
{
    __shared__ float W1s[NB*HR];            // 2 KB
    __shared__ float b1s[HR];
    __shared__ ushort_t hB[4][16][72];      // 9.2 KB
    __shared__ ushort_t rwS[4][16][132];    // 16.9 KB (132-stride: conflict-free C writes)
    __shared__ int sndS[64], rowS[64];

    const int t = threadIdx.x;
    const int wv = t >> 6;
    const int lane = t & 63;
    const int j64 = lane;
    const int r16 = lane & 15;
    const int quad = lane >> 4;
    const int p0b = blockIdx.x * 64;

    W1s[t] = rW1[layer*NB*HR + t];
    W1s[256 + t] = rW1[layer*NB*HR + 256 + t];
    if (t < HR) b1s[t] = rb1[layer*HR + t];
    if (t < 64) { sndS[t] = sndrow[p0b + t]; rowS[t] = rcvrow[p0b + t]; }
    __syncthreads();

    // phase A: h (bf16) for this wave's 16 positions
    const int p0 = p0b + wv*16;
    #pragma unroll 4
    for (int e = 0; e < 16; ++e) {
        const float4* B4 = (const float4*)(basis_pos + (size_t)(p0 + e)*8);
        float4 x0 = B4[0], x1 = B4[1];
        float a = b1s[j64];
        a = fmaf(x0.x, W1s[0*HR + j64], a);
        a = fmaf(x0.y, W1s[1*HR + j64], a);
        a = fmaf(x0.z, W1s[2*HR + j64], a);
        a = fmaf(x0.w, W1s[3*HR + j64], a);
        a = fmaf(x1.x, W1s[4*HR + j64], a);
        a = fmaf(x1.y, W1s[5*HR + j64], a);
        a = fmaf(x1.z, W1s[6*HR + j64], a);
        a = fmaf(x1.w, W1s[7*HR + j64], a);
        hB[wv][e][j64] = f2bf(a / (1.f + expf(-a)));
    }
    // phase B: MFMA rw = h(16x64) @ W2_l0(64x128) -> LDS bf16 (per-wave)
    {
        short8 a0 = *(const short8*)&hB[wv][r16][quad*8];
        short8 a1 = *(const short8*)&hB[wv][r16][32 + quad*8];
        const ushort_t* W2l = W2T0 + layer*8192;
        #pragma unroll
        for (int nt = 0; nt < 8; ++nt) {
            const int col = nt*16 + r16;
            short8 b0 = *(const short8*)(W2l + (size_t)col*64 + quad*8);
            short8 b1 = *(const short8*)(W2l + (size_t)col*64 + 32 + quad*8);
            f32x4 c = (f32x4){0.f, 0.f, 0.f, 0.f};
            c = __builtin_amdgcn_mfma_f32_16x16x32_bf16(a0, b0, c, 0, 0, 0);
            c = __builtin_amdgcn_mfma_f32_16x16x32_bf16(a1, b1, c, 0, 0, 0);
            #pragma unroll
            for (int r = 0; r < 4; ++r)
                rwS[wv][quad*4 + r][col] = f2bf(c[r]);
        }
    }
    __syncthreads();

    // phase C: scan 32 CSR-contiguous positions (receivers non-decreasing), flush runs
    {
        const int f = t & 127, mh = t >> 7;
        const int base = mh*32;
        int cur = rowS[base];
        float acc = 0.f;
        #pragma unroll 8
        for (int i = 0; i < 32; ++i) {
            const int pl = base + i;
            const int row = rowS[pl];
            const float sf = bfu(fB_in[(size_t)sndS[pl]*128 + f]);
            const float rl = bfu(rwS[pl >> 4][pl & 15][f]);
            if (row != cur) {
                atomicAdd(&aggF[(size_t)cur*128 + f], acc);
                cur = row; acc = 0.f;
            }
            acc = fmaf(sf, rl, acc);
        }
        atomicAdd(&aggF[(size_t)cur*128 + f], acc);
    }
}

// ---- tile -> species from psptr (10-step scan) ----
__device__ __forceinline__ int tile_to_spec(const int* __restrict__ psptr, int tile)
{
    int spec = 0;
    const int row = tile*16;
    #pragma unroll
    for (int s = 1; s < NSPEC; ++s)
        if (row >= psptr[s]) spec = s;
    return spec;
}

// ---- 7: layer-0 gemm+epi: lin GEMM + poly + fB1 + readout0; re-zeroes aggF tile ----
__global__ __launch_bounds__(256) void k_gemm_epi0(
    float* __restrict__ aggF,
    const ushort_t* __restrict__ WBlin0,
    const int* __restrict__ scnt, const int* __restrict__ sptr,
    const int* __restrict__ psptr, const int* __restrict__ perm,
    const float* __restrict__ prodc, const float* __restrict__ ro0,
    ushort_t* __restrict__ fB1, float* __restrict__ out)
{
    __shared__ float redS[16][65];
    const int tile = blockIdx.x;
    const int spec = tile_to_spec(psptr, tile);
    const int t = threadIdx.x;
    const int lane = t & 63;
    const int wv = t >> 6;
    const int r16 = lane & 15;
    const int quad = lane >> 4;

    float* Ap = aggF + (size_t)tile*2048;
    const ushort_t* Wp = WBlin0 + (size_t)spec*16384;
    const float* pc = prodc + (size_t)spec*3*F;

    short8 a[4];
    #pragma unroll
    for (int c = 0; c < 4; ++c)
        a[c] = pack8(Ap + (size_t)r16*128 + c*32 + quad*8);
    __syncthreads();   // all waves' reads done
    {   // zero tile for layer-1 atomic reuse
        f32x4 z = (f32x4){0.f, 0.f, 0.f, 0.f};
        *(f32x4*)(Ap + t*8) = z;
        *(f32x4*)(Ap + t*8 + 4) = z;
    }

    float pr[4] = {0.f, 0.f, 0.f, 0.f};
    #pragma unroll
    for (int nt = 0; nt < 2; ++nt) {
        const int col = wv*32 + nt*16 + r16;
        f32x4 acc = (f32x4){0.f, 0.f, 0.f, 0.f};
        #pragma unroll
        for (int c = 0; c < 4; ++c) {
            short8 b = *(const short8*)(Wp + (size_t)col*128 + c*32 + quad*8);
            acc = __builtin_amdgcn_mfma_f32_16x16x32_bf16(a[c], b, acc, 0, 0, 0);
        }
        const float w0 = ro0[col];
        const float p0c = pc[col], p1c = pc[F+col], p2c = pc[2*F+col];
        #pragma unroll
        for (int r = 0; r < 4; ++r) {
            float s = acc[r] * 0.5f;
            float val = s * (p0c + p1c*s + p2c*s*s);
            fB1[((size_t)tile*16 + quad*4 + r)*128 + col] = f2bf(val);
            pr[r] = fmaf(val, w0, pr[r]);
        }
    }
    #pragma unroll
    for (int r = 0; r < 4; ++r) redS[quad*4 + r][wv*16 + r16] = pr[r];
    __syncthreads();
    if (t < 16) {
        int rel = tile*16 + t - psptr[spec];
        if (rel >= 0 && rel < scnt[spec]) {
            float s = 0.f;
            for (int j = 0; j < 64; ++j) s += redS[t][j];
            out[(size_t)perm[sptr[spec] + rel]*2 + 0] = s;
        }
    }
}

// ---- 8: layer-1 gemm+epi: lin+sc GEMM + poly + MLP readout1 ----
__global__ __launch_bounds__(256) void k_gemm_epi1(
    const float* __restrict__ aggF,
    const ushort_t* __restrict__ fB1,
    const ushort_t* __restrict__ WBlin1, const ushort_t* __restrict__ WBsc0,
    const int* __restrict__ scnt, const int* __restrict__ sptr,
    const int* __restrict__ psptr, const int* __restrict__ perm,
    const float* __restrict__ prodc,
    const float* __restrict__ ro1W1, const float* __restrict__ ro1W2,
    float* __restrict__ out)
{
    __shared__ float sS[16][132];
    __shared__ float yS[16][17];
    const int tile = blockIdx.x;
    const int spec = tile_to_spec(psptr, tile);
    const int t = threadIdx.x;
    const int lane = t & 63;
    const int wv = t >> 6;
    const int r16 = lane & 15;
    const int quad = lane >> 4;

    const float* Ap = aggF + (size_t)tile*2048;
    const ushort_t* Fp = fB1 + (size_t)tile*16*128;
    const ushort_t* Wl = WBlin1 + (size_t)spec*16384;
    const ushort_t* Ws = WBsc0  + (size_t)spec*16384;
    const float* pc = prodc + ((size_t)NSPEC + spec)*3*F;

    short8 a1[4], a2[4];
    #pragma unroll
    for (int c = 0; c < 4; ++c) {
        a1[c] = pack8(Ap + (size_t)r16*128 + c*32 + quad*8);
        a2[c] = *(const short8*)(Fp + (size_t)r16*128 + c*32 + quad*8);
    }
    #pragma unroll
    for (int nt = 0; nt < 2; ++nt) {
        const int col = wv*32 + nt*16 + r16;
        f32x4 accl = (f32x4){0.f, 0.f, 0.f, 0.f};
        f32x4 accs = (f32x4){0.f, 0.f, 0.f, 0.f};
        #pragma unroll
        for (int c = 0; c < 4; ++c) {
            short8 bl = *(const short8*)(Wl + (size_t)col*128 + c*32 + quad*8);
            short8 bs = *(const short8*)(Ws + (size_t)col*128 + c*32 + quad*8);
            accl = __builtin_amdgcn_mfma_f32_16x16x32_bf16(a1[c], bl, accl, 0, 0, 0);
            accs = __builtin_amdgcn_mfma_f32_16x16x32_bf16(a2[c], bs, accs, 0, 0, 0);
        }
        const float p0c = pc[col], p1c = pc[F+col], p2c = pc[2*F+col];
        #pragma unroll
        for (int r = 0; r < 4; ++r) {
            float s = accl[r] * 0.5f;
            sS[quad*4 + r][col] = s * (p0c + p1c*s + p2c*s*s) + accs[r];
        }
    }
    __syncthreads();
    {
        const int node = t >> 4, c = t & 15;
        float a = 0.f;
        #pragma unroll 8
        for (int g = 0; g < F; ++g) a = fmaf(sS[node][g], ro1W1[g*16 + c], a);
        a = silu_f(a);
        yS[node][c] = a * ro1W2[c];
    }
    __syncthreads();
    if (t < 16) {
        int rel = tile*16 + t - psptr[spec];
        if (rel >= 0 && rel < scnt[spec]) {
            float s = 0.f;
            #pragma unroll
            for (int j = 0; j < 16; ++j) s += yS[t][j];
            out[(size_t)perm[sptr[spec] + rel]*2 + 1] = s;
        }
    }
}

extern "C" void kernel_launch(void* const* d_in, const int* in_sizes, int n_in,
                              void* d_out, int out_size, void* d_ws, size_t ws_size,
                              hipStream_t stream)
{
    (void)in_sizes; (void)n_in; (void)out_size; (void)ws_size;
    const float* vectors   = (const float*)d_in[0];
    const int*   spec      = (const int*)d_in[1];
    const int*   senders   = (const int*)d_in[2];
    const int*   receivers = (const int*)d_in[3];
    const float* embW      = (const float*)d_in[4];
    const float* rW1       = (const float*)d_in[5];
    const float* rb1       = (const float*)d_in[6];
    const float* rW2       = (const float*)d_in[7];
    const float* linW      = (const float*)d_in[8];
    const float* prodc     = (const float*)d_in[9];
    const float* scW       = (const float*)d_in[10];
    const float* ro0       = (const float*)d_in[11];
    const float* ro1W1     = (const float*)d_in[12];
    const float* ro1W2     = (const float*)d_in[13];
    float* out = (float*)d_out;

    char* ws = (char*)d_ws;
    float*    basis_pos = (float*)ws;    ws += sizeof(float)*(size_t)N_EDGES*8;
    float*    aggF      = (float*)ws;    ws += sizeof(float)*(size_t)NPAD*128;
    ushort_t* fB0       = (ushort_t*)ws; ws += sizeof(ushort_t)*(size_t)NPAD*128;
    ushort_t* fB1       = (ushort_t*)ws; ws += sizeof(ushort_t)*(size_t)NPAD*128;
    ushort_t* WBlin0    = (ushort_t*)ws; ws += sizeof(ushort_t)*(size_t)2*NSPEC*16384;
    ushort_t* WBsc0     = (ushort_t*)ws; ws += sizeof(ushort_t)*(size_t)NSPEC*16384;
    ushort_t* W2T0      = (ushort_t*)ws; ws += sizeof(ushort_t)*(size_t)2*128*64;
    int* sndrow    = (int*)ws; ws += sizeof(int)*N_EDGES;
    int* rcvrow    = (int*)ws; ws += sizeof(int)*N_EDGES;
    int* row_ptr   = (int*)ws; ws += sizeof(int)*(N_NODES+1);
    int* counts    = (int*)ws; ws += sizeof(int)*N_NODES;   // zero region start
    int* cursor    = (int*)ws; ws += sizeof(int)*N_NODES;
    int* scnt      = (int*)ws; ws += sizeof(int)*16;
    int* scur      = (int*)ws; ws += sizeof(int)*16;
    int* sptr      = (int*)ws; ws += sizeof(int)*16;
    int* psptr     = (int*)ws; ws += sizeof(int)*16;
    int* perm      = (int*)ws; ws += sizeof(int)*N_NODES;
    int* inv       = (int*)ws; ws += sizeof(int)*N_NODES;
    int* specS     = (int*)ws; ws += sizeof(int)*N_NODES;
    int* pn        = (int*)ws; ws += sizeof(int)*N_NODES;

    const int EB = (N_EDGES + 255)/256;

    k_conv_zero<<<1984, 256, 0, stream>>>(linW, scW, rW2, WBlin0, WBsc0, W2T0, counts, aggF);
    k_hist<<<EB, 256, 0, stream>>>(spec, receivers, scnt, counts);
    k_sfill<<<(N_NODES + 255)/256, 256, 0, stream>>>(spec, scnt, sptr, psptr, scur,
                                                     perm, inv, specS, pn);
    k_scan_init<<<1 + (N_NODES*F + 255)/256, 256, 0, stream>>>(counts, perm, row_ptr,
                                                               specS, pn, embW, fB0);
    k_fill_pre<<<EB, 256, 0, stream>>>(receivers, senders, inv, pn, row_ptr, cursor,
                                       vectors, basis_pos, sndrow, rcvrow);

    // layer 0
    k_rwagg<<<ETILES, 256, 0, stream>>>(0, basis_pos, rW1, rb1, W2T0,
                                        sndrow, rcvrow, fB0, aggF);
    k_gemm_epi0<<<NT_MAX, 256, 0, stream>>>(aggF, WBlin0, scnt, sptr, psptr, perm,
                                            prodc, ro0, fB1, out);
    // layer 1
    k_rwagg<<<ETILES, 256, 0, stream>>>(1, basis_pos, rW1, rb1, W2T0,
                                        sndrow, rcvrow, fB1, aggF);
    k_gemm_epi1<<<NT_MAX, 256, 0, stream>>>(aggF, fB1, WBlin0 + (size_t)NSPEC*16384, WBsc0,
                                            scnt, sptr, psptr, perm, prodc, ro1W1, ro1W2, out);
}

// Round 20
// 315.236 us; speedup vs baseline: 1.0067x; 1.0067x over previous
//
#include <hip/hip_runtime.h>
#include <math.h>
#include <stdint.h>

#define N_NODES 10000
#define N_EDGES 160000
#define F 128
#define NB 8
#define HR 64
#define NSPEC 10
#define PI_F 3.14159265358979323846f
#define NPAD 10160
#define NT_MAX 635
#define ETILES 2500

typedef unsigned short ushort_t;
typedef __attribute__((ext_vector_type(8))) short short8;
typedef __attribute__((ext_vector_type(4))) float f32x4;

__device__ __forceinline__ float silu_f(float x){ return x / (1.f + expf(-x)); }
__device__ __forceinline__ float bfu(ushort_t u) {
    union { unsigned int i; float f; } v; v.i = ((unsigned int)u) << 16; return v.f;
}
__device__ __forceinline__ ushort_t f2bf(float f) {
    union { float f; unsigned int i; } v; v.f = f;
    unsigned int x = v.i;
    unsigned int r = (x + 0x7fffu + ((x >> 16) & 1u)) >> 16;
    return (ushort_t)r;
}
__device__ __forceinline__ short8 pack8(const float* p) {
    short8 r;
    #pragma unroll
    for (int i = 0; i < 8; ++i) r[i] = (short)f2bf(p[i]);
    return r;
}

// ---- 1: zero counters + aggF + convert weights ----
__global__ __launch_bounds__(256) void k_conv_zero(
    const float* __restrict__ linW, const float* __restrict__ scW, const float* __restrict__ rW2,
    ushort_t* __restrict__ WBlin0, ushort_t* __restrict__ WBsc0, ushort_t* __restrict__ W2T0,
    int* __restrict__ zero_base, float* __restrict__ aggF)
{
    const int gtid = blockIdx.x*256 + threadIdx.x;
    const int GRID = 1984*256;
    for (int i = gtid; i < 2*N_NODES + 32; i += GRID) zero_base[i] = 0;
    for (int i = gtid; i < NPAD*128; i += GRID) aggF[i] = 0.f;
    const int LINTOT = 2*NSPEC*16384;
    const int SCTOT  = NSPEC*16384;
    int i = gtid;
    if (i < LINTOT) {
        int mat = i >> 14;
        int r = i & 16383;
        int fo = r >> 7, fi = r & 127;
        WBlin0[(size_t)mat*16384 + fo*128 + fi] =
            f2bf(linW[((size_t)mat*4 + 0)*16384 + fi*128 + fo]);
    } else if (i < LINTOT + SCTOT) {
        int t2 = i - LINTOT;
        int sp = t2 >> 14;
        int r = t2 & 16383;
        int fo = r >> 7, fi = r & 127;
        WBsc0[(size_t)sp*16384 + fo*128 + fi] =
            f2bf(scW[((size_t)(NSPEC + sp)*4 + 0)*16384 + fi*128 + fo]);
    } else if (i < LINTOT + SCTOT + 2*128*64) {
        int t2 = i - LINTOT - SCTOT;
        int l = t2 >> 13; int r = t2 & 8191; int f = r >> 6; int k = r & 63;
        W2T0[t2] = f2bf(rW2[(size_t)l*HR*512 + (size_t)k*512 + 4*f]);
    }
}

// ---- 2: both histograms (raw ids) ----
__global__ void k_hist(const int* __restrict__ spec, const int* __restrict__ recv,
                       int* __restrict__ scnt, int* __restrict__ counts)
{
    int i = blockIdx.x*256 + threadIdx.x;
    if (i < N_EDGES) atomicAdd(&counts[recv[i]], 1);
    if (i < N_NODES) atomicAdd(&scnt[spec[i]], 1);
}

// ---- 3: sort fill with per-block local species scan; block 0 publishes sptr/psptr ----
__global__ __launch_bounds__(256) void k_sfill(
    const int* __restrict__ spec, const int* __restrict__ scnt,
    int* __restrict__ sptr, int* __restrict__ psptr,
    int* __restrict__ scur, int* __restrict__ perm,
    int* __restrict__ inv, int* __restrict__ specS, int* __restrict__ pn)
{
    __shared__ int sptrL[NSPEC+1], psptrL[NSPEC+1];
    const int t = threadIdx.x;
    if (t == 0) {
        int acc = 0, pacc = 0;
        for (int s = 0; s < NSPEC; ++s) {
            sptrL[s] = acc; psptrL[s] = pacc;
            acc += scnt[s];
            pacc += ((scnt[s] + 15) >> 4) << 4;
        }
        sptrL[NSPEC] = acc; psptrL[NSPEC] = pacc;
        if (blockIdx.x == 0) {
            for (int s = 0; s <= NSPEC; ++s) { sptr[s] = sptrL[s]; psptr[s] = psptrL[s]; }
        }
    }
    __syncthreads();
    int n = blockIdx.x*256 + t;
    if (n >= N_NODES) return;
    int s = spec[n];
    int pos = sptrL[s] + atomicAdd(&scur[s], 1);
    perm[pos] = n; inv[n] = pos; specS[pos] = s;
    pn[pos] = psptrL[s] + (pos - sptrL[s]);
}

// ---- 4: row_ptr scan (block 0) + fB0 init (other blocks) ----
__global__ __launch_bounds__(256) void k_scan_init(
    const int* __restrict__ counts, const int* __restrict__ perm, int* __restrict__ row_ptr,
    const int* __restrict__ specS, const int* __restrict__ pn,
    const float* __restrict__ embW, ushort_t* __restrict__ fB0)
{
    const int t = threadIdx.x;
    if (blockIdx.x == 0) {
        __shared__ int ps[256];
        int loc[40];
        int sum = 0;
        int base = t * 40;
        #pragma unroll
        for (int j = 0; j < 40; ++j) {
            int idx = base + j;
            int c = (idx < N_NODES) ? counts[perm[idx]] : 0;
            loc[j] = c; sum += c;
        }
        ps[t] = sum;
        __syncthreads();
        for (int off = 1; off < 256; off <<= 1) {
            int v = (t >= off) ? ps[t-off] : 0;
            __syncthreads();
            ps[t] += v;
            __syncthreads();
        }
        int ex = ps[t] - sum;
        #pragma unroll
        for (int j = 0; j < 40; ++j) {
            int idx = base + j;
            if (idx < N_NODES) row_ptr[idx] = ex;
            ex += loc[j];
        }
        if (t == 255) row_ptr[N_NODES] = ex;
    } else {
        int i = (blockIdx.x - 1)*256 + t;
        if (i < N_NODES*F) {
            int n = i >> 7, f = i & 127;
            fB0[(size_t)pn[n]*128 + f] = f2bf(embW[specS[n]*F + f]);
        }
    }
}

// ---- 5: CSR fill + basis + sender/receiver rows ----
__global__ void k_fill_pre(const int* __restrict__ recv, const int* __restrict__ senders,
                           const int* __restrict__ inv, const int* __restrict__ pn,
                           const int* __restrict__ row_ptr, int* __restrict__ cursor,
                           const float* __restrict__ vec,
                           float* __restrict__ basis_pos, int* __restrict__ sndrow,
                           int* __restrict__ rcvrow)
{
    int e = blockIdx.x*256 + threadIdx.x;
    if (e >= N_EDGES) return;
    int r = inv[recv[e]];
    int q = row_ptr[r] + atomicAdd(&cursor[r], 1);
    sndrow[q] = pn[inv[senders[e]]];
    rcvrow[q] = pn[r];
    float x = vec[e*3+0], y = vec[e*3+1], z = vec[e*3+2];
    float rr = sqrtf(x*x + y*y + z*z);
    rr = fmaxf(rr, 1e-9f);
    float rc = fminf(rr, 5.0f);
    float cut = 0.5f * (cosf(PI_F * rc * 0.2f) + 1.f);
    float pref = sqrtf(0.4f) * cut / rr;
    float B[8];
    #pragma unroll
    for (int k = 1; k <= 8; ++k) B[k-1] = pref * sinf(PI_F * 0.2f * (float)k * rr);
    float4* dst = (float4*)(basis_pos + (size_t)q*8);
    dst[0] = make_float4(B[0], B[1], B[2], B[3]);
    dst[1] = make_float4(B[4], B[5], B[6], B[7]);
}

// ---- 6: fused radial MLP + aggregation for one layer: aggF[row][f] += scal*rw ----
// 2500 blocks x 64 positions; h and rw share one per-wave LDS buffer (overlay) -> ~19.8 KB, 8 blocks/CU
__global__ __launch_bounds__(256) void k_rwagg(
    const int layer,
    const float* __restrict__ basis_pos,
    const float* __restrict__ rW1,
    const float* __restrict__ rb1,
    const ushort_t* __restrict__ W2T0,
    const int* __restrict__ sndrow,
    const int* __restrict__ rcvrow,
    const ushort_t* __restrict__ fB_in,
    float* __restrict__ aggF)
{
    __shared__ float W1s[NB*HR];            // 2 KB
    __shared__ float b1s[HR];               // 256 B
    __shared__ ushort_t buf[4][16*132];     // 16.9 KB per-wave overlay: h (cols 0..71) then rw (cols 0..127)
    __shared__ int sndS[64], rowS[64];

    const int t = threadIdx.x;
    const int wv = t >> 6;
    const int lane = t & 63;
    const int j64 = lane;
    const int r16 = lane & 15;
    const int quad = lane >> 4;
    const int p0b = blockIdx.x * 64;

    W1s[t] = rW1[layer*NB*HR + t];
    W1s[256 + t] = rW1[layer*NB*HR + 256 + t];
    if (t < HR) b1s[t] = rb1[layer*HR + t];
    if (t < 64) { sndS[t] = sndrow[p0b + t]; rowS[t] = rcvrow[p0b + t]; }
    __syncthreads();

    // phase A: h (bf16) for this wave's 16 positions -> buf rows (stride 132)
    const int p0 = p0b + wv*16;
    #pragma unroll 4
    for (int e = 0; e < 16; ++e) {
        const float4* B4 = (const float4*)(basis_pos + (size_t)(p0 + e)*8);
        float4 x0 = B4[0], x1 = B4[1];
        float a = b1s[j64];
        a = fmaf(x0.x, W1s[0*HR + j64], a);
        a = fmaf(x0.y, W1s[1*HR + j64], a);
        a = fmaf(x0.z, W1s[2*HR + j64], a);
        a = fmaf(x0.w, W1s[3*HR + j64], a);
        a = fmaf(x1.x, W1s[4*HR + j64], a);
        a = fmaf(x1.y, W1s[5*HR + j64], a);
        a = fmaf(x1.z, W1s[6*HR + j64], a);
        a = fmaf(x1.w, W1s[7*HR + j64], a);
        buf[wv][e*132 + j64] = f2bf(a / (1.f + expf(-a)));
    }
    // phase B: load A-fragments (h dies here), MFMA, overwrite buf with rw
    {
        short8 a0 = *(const short8*)&buf[wv][r16*132 + quad*8];
        short8 a1 = *(const short8*)&buf[wv][r16*132 + 32 + quad*8];
        const ushort_t* W2l = W2T0 + layer*8192;
        #pragma unroll
        for (int nt = 0; nt < 8; ++nt) {
            const int col = nt*16 + r16;
            short8 b0 = *(const short8*)(W2l + (size_t)col*64 + quad*8);
            short8 b1 = *(const short8*)(W2l + (size_t)col*64 + 32 + quad*8);
            f32x4 c = (f32x4){0.f, 0.f, 0.f, 0.f};
            c = __builtin_amdgcn_mfma_f32_16x16x32_bf16(a0, b0, c, 0, 0, 0);
            c = __builtin_amdgcn_mfma_f32_16x16x32_bf16(a1, b1, c, 0, 0, 0);
            #pragma unroll
            for (int r = 0; r < 4; ++r)
                buf[wv][(quad*4 + r)*132 + col] = f2bf(c[r]);
        }
    }
    __syncthreads();

    // phase C: scan 32 CSR-contiguous positions (receivers non-decreasing), flush runs
    {
        const int f = t & 127, mh = t >> 7;
        const int base = mh*32;
        int cur = rowS[base];
        float acc = 0.f;
        #pragma unroll 8
        for (int i = 0; i < 32; ++i) {
            const int pl = base + i;
            const int row = rowS[pl];
            const float sf = bfu(fB_in[(size_t)sndS[pl]*128 + f]);
            const float rl = bfu(buf[pl >> 4][(pl & 15)*132 + f]);
            if (row != cur) {
                atomicAdd(&aggF[(size_t)cur*128 + f], acc);
                cur = row; acc = 0.f;
            }
            acc = fmaf(sf, rl, acc);
        }
        atomicAdd(&aggF[(size_t)cur*128 + f], acc);
    }
}

// ---- tile -> species from psptr (10-step scan) ----
__device__ __forceinline__ int tile_to_spec(const int* __restrict__ psptr, int tile)
{
    int spec = 0;
    const int row = tile*16;
    #pragma unroll
    for (int s = 1; s < NSPEC; ++s)
        if (row >= psptr[s]) spec = s;
    return spec;
}

// ---- 7: layer-0 gemm+epi: lin GEMM + poly + fB1 + readout0; re-zeroes aggF tile ----
__global__ __launch_bounds__(256) void k_gemm_epi0(
    float* __restrict__ aggF,
    const ushort_t* __restrict__ WBlin0,
    const int* __restrict__ scnt, const int* __restrict__ sptr,
    const int* __restrict__ psptr, const int* __restrict__ perm,
    const float* __restrict__ prodc, const float* __restrict__ ro0,
    ushort_t* __restrict__ fB1, float* __restrict__ out)
{
    __shared__ float redS[16][65];
    const int tile = blockIdx.x;
    const int spec = tile_to_spec(psptr, tile);
    const int t = threadIdx.x;
    const int lane = t & 63;
    const int wv = t >> 6;
    const int r16 = lane & 15;
    const int quad = lane >> 4;

    float* Ap = aggF + (size_t)tile*2048;
    const ushort_t* Wp = WBlin0 + (size_t)spec*16384;
    const float* pc = prodc + (size_t)spec*3*F;

    short8 a[4];
    #pragma unroll
    for (int c = 0; c < 4; ++c)
        a[c] = pack8(Ap + (size_t)r16*128 + c*32 + quad*8);
    __syncthreads();   // all waves' reads done
    {   // zero tile for layer-1 atomic reuse
        f32x4 z = (f32x4){0.f, 0.f, 0.f, 0.f};
        *(f32x4*)(Ap + t*8) = z;
        *(f32x4*)(Ap + t*8 + 4) = z;
    }

    float pr[4] = {0.f, 0.f, 0.f, 0.f};
    #pragma unroll
    for (int nt = 0; nt < 2; ++nt) {
        const int col = wv*32 + nt*16 + r16;
        f32x4 acc = (f32x4){0.f, 0.f, 0.f, 0.f};
        #pragma unroll
        for (int c = 0; c < 4; ++c) {
            short8 b = *(const short8*)(Wp + (size_t)col*128 + c*32 + quad*8);
            acc = __builtin_amdgcn_mfma_f32_16x16x32_bf16(a[c], b, acc, 0, 0, 0);
        }
        const float w0 = ro0[col];
        const float p0c = pc[col], p1c = pc[F+col], p2c = pc[2*F+col];
        #pragma unroll
        for (int r = 0; r < 4; ++r) {
            float s = acc[r] * 0.5f;
            float val = s * (p0c + p1c*s + p2c*s*s);
            fB1[((size_t)tile*16 + quad*4 + r)*128 + col] = f2bf(val);
            pr[r] = fmaf(val, w0, pr[r]);
        }
    }
    #pragma unroll
    for (int r = 0; r < 4; ++r) redS[quad*4 + r][wv*16 + r16] = pr[r];
    __syncthreads();
    if (t < 16) {
        int rel = tile*16 + t - psptr[spec];
        if (rel >= 0 && rel < scnt[spec]) {
            float s = 0.f;
            for (int j = 0; j < 64; ++j) s += redS[t][j];
            out[(size_t)perm[sptr[spec] + rel]*2 + 0] = s;
        }
    }
}

// ---- 8: layer-1 gemm+epi: lin+sc GEMM + poly + MLP readout1 ----
__global__ __launch_bounds__(256) void k_gemm_epi1(
    const float* __restrict__ aggF,
    const ushort_t* __restrict__ fB1,
    const ushort_t* __restrict__ WBlin1, const ushort_t* __restrict__ WBsc0,
    const int* __restrict__ scnt, const int* __restrict__ sptr,
    const int* __restrict__ psptr, const int* __restrict__ perm,
    const float* __restrict__ prodc,
    const float* __restrict__ ro1W1, const float* __restrict__ ro1W2,
    float* __restrict__ out)
{
    __shared__ float sS[16][132];
    __shared__ float yS[16][17];
    const int tile = blockIdx.x;
    const int spec = tile_to_spec(psptr, tile);
    const int t = threadIdx.x;
    const int lane = t & 63;
    const int wv = t >> 6;
    const int r16 = lane & 15;
    const int quad = lane >> 4;

    const float* Ap = aggF + (size_t)tile*2048;
    const ushort_t* Fp = fB1 + (size_t)tile*16*128;
    const ushort_t* Wl = WBlin1 + (size_t)spec*16384;
    const ushort_t* Ws = WBsc0  + (size_t)spec*16384;
    const float* pc = prodc + ((size_t)NSPEC + spec)*3*F;

    short8 a1[4], a2[4];
    #pragma unroll
    for (int c = 0; c < 4; ++c) {
        a1[c] = pack8(Ap + (size_t)r16*128 + c*32 + quad*8);
        a2[c] = *(const short8*)(Fp + (size_t)r16*128 + c*32 + quad*8);
    }
    #pragma unroll
    for (int nt = 0; nt < 2; ++nt) {
        const int col = wv*32 + nt*16 + r16;
        f32x4 accl = (f32x4){0.f, 0.f, 0.f, 0.f};
        f32x4 accs = (f32x4){0.f, 0.f, 0.f, 0.f};
        #pragma unroll
        for (int c = 0; c < 4; ++c) {
            short8 bl = *(const short8*)(Wl + (size_t)col*128 + c*32 + quad*8);
            short8 bs = *(const short8*)(Ws + (size_t)col*128 + c*32 + quad*8);
            accl = __builtin_amdgcn_mfma_f32_16x16x32_bf16(a1[c], bl, accl, 0, 0, 0);
            accs = __builtin_amdgcn_mfma_f32_16x16x32_bf16(a2[c], bs, accs, 0, 0, 0);
        }
        const float p0c = pc[col], p1c = pc[F+col], p2c = pc[2*F+col];
        #pragma unroll
        for (int r = 0; r < 4; ++r) {
            float s = accl[r] * 0.5f;
            sS[quad*4 + r][col] = s * (p0c + p1c*s + p2c*s*s) + accs[r];
        }
    }
    __syncthreads();
    {
        const int node = t >> 4, c = t & 15;
        float a = 0.f;
        #pragma unroll 8
        for (int g = 0; g < F; ++g) a = fmaf(sS[node][g], ro1W1[g*16 + c], a);
        a = silu_f(a);
        yS[node][c] = a * ro1W2[c];
    }
    __syncthreads();
    if (t < 16) {
        int rel = tile*16 + t - psptr[spec];
        if (rel >= 0 && rel < scnt[spec]) {
            float s = 0.f;
            #pragma unroll
            for (int j = 0; j < 16; ++j) s += yS[t][j];
            out[(size_t)perm[sptr[spec] + rel]*2 + 1] = s;
        }
    }
}

extern "C" void kernel_launch(void* const* d_in, const int* in_sizes, int n_in,
                              void* d_out, int out_size, void* d_ws, size_t ws_size,
                              hipStream_t stream)
{
    (void)in_sizes; (void)n_in; (void)out_size; (void)ws_size;
    const float* vectors   = (const float*)d_in[0];
    const int*   spec      = (const int*)d_in[1];
    const int*   senders   = (const int*)d_in[2];
    const int*   receivers = (const int*)d_in[3];
    const float* embW      = (const float*)d_in[4];
    const float* rW1       = (const float*)d_in[5];
    const float* rb1       = (const float*)d_in[6];
    const float* rW2       = (const float*)d_in[7];
    const float* linW      = (const float*)d_in[8];
    const float* prodc     = (const float*)d_in[9];
    const float* scW       = (const float*)d_in[10];
    const float* ro0       = (const float*)d_in[11];
    const float* ro1W1     = (const float*)d_in[12];
    const float* ro1W2     = (const float*)d_in[13];
    float* out = (float*)d_out;

    char* ws = (char*)d_ws;
    float*    basis_pos = (float*)ws;    ws += sizeof(float)*(size_t)N_EDGES*8;
    float*    aggF      = (float*)ws;    ws += sizeof(float)*(size_t)NPAD*128;
    ushort_t* fB0       = (ushort_t*)ws; ws += sizeof(ushort_t)*(size_t)NPAD*128;
    ushort_t* fB1       = (ushort_t*)ws; ws += sizeof(ushort_t)*(size_t)NPAD*128;
    ushort_t* WBlin0    = (ushort_t*)ws; ws += sizeof(ushort_t)*(size_t)2*NSPEC*16384;
    ushort_t* WBsc0     = (ushort_t*)ws; ws += sizeof(ushort_t)*(size_t)NSPEC*16384;
    ushort_t* W2T0      = (ushort_t*)ws; ws += sizeof(ushort_t)*(size_t)2*128*64;
    int* sndrow    = (int*)ws; ws += sizeof(int)*N_EDGES;
    int* rcvrow    = (int*)ws; ws += sizeof(int)*N_EDGES;
    int* row_ptr   = (int*)ws; ws += sizeof(int)*(N_NODES+1);
    int* counts    = (int*)ws; ws += sizeof(int)*N_NODES;   // zero region start
    int* cursor    = (int*)ws; ws += sizeof(int)*N_NODES;
    int* scnt      = (int*)ws; ws += sizeof(int)*16;
    int* scur      = (int*)ws; ws += sizeof(int)*16;
    int* sptr      = (int*)ws; ws += sizeof(int)*16;
    int* psptr     = (int*)ws; ws += sizeof(int)*16;
    int* perm      = (int*)ws; ws += sizeof(int)*N_NODES;
    int* inv       = (int*)ws; ws += sizeof(int)*N_NODES;
    int* specS     = (int*)ws; ws += sizeof(int)*N_NODES;
    int* pn        = (int*)ws; ws += sizeof(int)*N_NODES;

    const int EB = (N_EDGES + 255)/256;

    k_conv_zero<<<1984, 256, 0, stream>>>(linW, scW, rW2, WBlin0, WBsc0, W2T0, counts, aggF);
    k_hist<<<EB, 256, 0, stream>>>(spec, receivers, scnt, counts);
    k_sfill<<<(N_NODES + 255)/256, 256, 0, stream>>>(spec, scnt, sptr, psptr, scur,
                                                     perm, inv, specS, pn);
    k_scan_init<<<1 + (N_NODES*F + 255)/256, 256, 0, stream>>>(counts, perm, row_ptr,
                                                               specS, pn, embW, fB0);
    k_fill_pre<<<EB, 256, 0, stream>>>(receivers, senders, inv, pn, row_ptr, cursor,
                                       vectors, basis_pos, sndrow, rcvrow);

    // layer 0
    k_rwagg<<<ETILES, 256, 0, stream>>>(0, basis_pos, rW1, rb1, W2T0,
                                        sndrow, rcvrow, fB0, aggF);
    k_gemm_epi0<<<NT_MAX, 256, 0, stream>>>(aggF, WBlin0, scnt, sptr, psptr, perm,
                                            prodc, ro0, fB1, out);
    // layer 1
    k_rwagg<<<ETILES, 256, 0, stream>>>(1, basis_pos, rW1, rb1, W2T0,
                                        sndrow, rcvrow, fB1, aggF);
    k_gemm_epi1<<<NT_MAX, 256, 0, stream>>>(aggF, fB1, WBlin0 + (size_t)NSPEC*16384, WBsc0,
                                            scnt, sptr, psptr, perm, prodc, ro1W1, ro1W2, out);
}

// Round 21
// 293.830 us; speedup vs baseline: 1.0800x; 1.0729x over previous
//
#include <hip/hip_runtime.h>
#include <math.h>
#include <stdint.h>

#define N_NODES 10000
#define N_EDGES 160000
#define F 128
#define NB 8
#define HR 64
#define NSPEC 10
#define PI_F 3.14159265358979323846f
#define NPAD 10160
#define NT_MAX 635
#define ETILES 2500

typedef unsigned short ushort_t;
typedef __attribute__((ext_vector_type(8))) short short8;
typedef __attribute__((ext_vector_type(4))) float f32x4;

__device__ __forceinline__ float silu_f(float x){ return x / (1.f + expf(-x)); }
__device__ __forceinline__ float bfu(ushort_t u) {
    union { unsigned int i; float f; } v; v.i = ((unsigned int)u) << 16; return v.f;
}
__device__ __forceinline__ ushort_t f2bf(float f) {
    union { float f; unsigned int i; } v; v.f = f;
    unsigned int x = v.i;
    unsigned int r = (x + 0x7fffu + ((x >> 16) & 1u)) >> 16;
    return (ushort_t)r;
}
__device__ __forceinline__ short8 pack8(const float* p) {
    short8 r;
    #pragma unroll
    for (int i = 0; i < 8; ++i) r[i] = (short)f2bf(p[i]);
    return r;
}

// ---- 1: zero counters + aggF + convert weights ----
__global__ __launch_bounds__(256) void k_conv_zero(
    const float* __restrict__ linW, const float* __restrict__ scW, const float* __restrict__ rW2,
    ushort_t* __restrict__ WBlin0, ushort_t* __restrict__ WBsc0, ushort_t* __restrict__ W2T0,
    int* __restrict__ zero_base, float* __restrict__ aggF)
{
    const int gtid = blockIdx.x*256 + threadIdx.x;
    const int GRID = 1984*256;
    for (int i = gtid; i < 2*N_NODES + 32; i += GRID) zero_base[i] = 0;
    for (int i = gtid; i < NPAD*128; i += GRID) aggF[i] = 0.f;
    const int LINTOT = 2*NSPEC*16384;
    const int SCTOT  = NSPEC*16384;
    int i = gtid;
    if (i < LINTOT) {
        int mat = i >> 14;
        int r = i & 16383;
        int fo = r >> 7, fi = r & 127;
        WBlin0[(size_t)mat*16384 + fo*128 + fi] =
            f2bf(linW[((size_t)mat*4 + 0)*16384 + fi*128 + fo]);
    } else if (i < LINTOT + SCTOT) {
        int t2 = i - LINTOT;
        int sp = t2 >> 14;
        int r = t2 & 16383;
        int fo = r >> 7, fi = r & 127;
        WBsc0[(size_t)sp*16384 + fo*128 + fi] =
            f2bf(scW[((size_t)(NSPEC + sp)*4 + 0)*16384 + fi*128 + fo]);
    } else if (i < LINTOT + SCTOT + 2*128*64) {
        int t2 = i - LINTOT - SCTOT;
        int l = t2 >> 13; int r = t2 & 8191; int f = r >> 6; int k = r & 63;
        W2T0[t2] = f2bf(rW2[(size_t)l*HR*512 + (size_t)k*512 + 4*f]);
    }
}

// ---- 2: both histograms (raw ids) ----
__global__ void k_hist(const int* __restrict__ spec, const int* __restrict__ recv,
                       int* __restrict__ scnt, int* __restrict__ counts)
{
    int i = blockIdx.x*256 + threadIdx.x;
    if (i < N_EDGES) atomicAdd(&counts[recv[i]], 1);
    if (i < N_NODES) atomicAdd(&scnt[spec[i]], 1);
}

// ---- 3: sort fill with per-block local species scan; block 0 publishes sptr/psptr ----
__global__ __launch_bounds__(256) void k_sfill(
    const int* __restrict__ spec, const int* __restrict__ scnt,
    int* __restrict__ sptr, int* __restrict__ psptr,
    int* __restrict__ scur, int* __restrict__ perm,
    int* __restrict__ inv, int* __restrict__ specS, int* __restrict__ pn)
{
    __shared__ int sptrL[NSPEC+1], psptrL[NSPEC+1];
    const int t = threadIdx.x;
    if (t == 0) {
        int acc = 0, pacc = 0;
        for (int s = 0; s < NSPEC; ++s) {
            sptrL[s] = acc; psptrL[s] = pacc;
            acc += scnt[s];
            pacc += ((scnt[s] + 15) >> 4) << 4;
        }
        sptrL[NSPEC] = acc; psptrL[NSPEC] = pacc;
        if (blockIdx.x == 0) {
            for (int s = 0; s <= NSPEC; ++s) { sptr[s] = sptrL[s]; psptr[s] = psptrL[s]; }
        }
    }
    __syncthreads();
    int n = blockIdx.x*256 + t;
    if (n >= N_NODES) return;
    int s = spec[n];
    int pos = sptrL[s] + atomicAdd(&scur[s], 1);
    perm[pos] = n; inv[n] = pos; specS[pos] = s;
    pn[pos] = psptrL[s] + (pos - sptrL[s]);
}

// ---- 4: row_ptr scan (block 0) + fB0 init (other blocks) ----
__global__ __launch_bounds__(256) void k_scan_init(
    const int* __restrict__ counts, const int* __restrict__ perm, int* __restrict__ row_ptr,
    const int* __restrict__ specS, const int* __restrict__ pn,
    const float* __restrict__ embW, ushort_t* __restrict__ fB0)
{
    const int t = threadIdx.x;
    if (blockIdx.x == 0) {
        __shared__ int ps[256];
        int loc[40];
        int sum = 0;
        int base = t * 40;
        #pragma unroll
        for (int j = 0; j < 40; ++j) {
            int idx = base + j;
            int c = (idx < N_NODES) ? counts[perm[idx]] : 0;
            loc[j] = c; sum += c;
        }
        ps[t] = sum;
        __syncthreads();
        for (int off = 1; off < 256; off <<= 1) {
            int v = (t >= off) ? ps[t-off] : 0;
            __syncthreads();
            ps[t] += v;
            __syncthreads();
        }
        int ex = ps[t] - sum;
        #pragma unroll
        for (int j = 0; j < 40; ++j) {
            int idx = base + j;
            if (idx < N_NODES) row_ptr[idx] = ex;
            ex += loc[j];
        }
        if (t == 255) row_ptr[N_NODES] = ex;
    } else {
        int i = (blockIdx.x - 1)*256 + t;
        if (i < N_NODES*F) {
            int n = i >> 7, f = i & 127;
            fB0[(size_t)pn[n]*128 + f] = f2bf(embW[specS[n]*F + f]);
        }
    }
}

// ---- 5: CSR fill + basis + sender/receiver rows ----
__global__ void k_fill_pre(const int* __restrict__ recv, const int* __restrict__ senders,
                           const int* __restrict__ inv, const int* __restrict__ pn,
                           const int* __restrict__ row_ptr, int* __restrict__ cursor,
                           const float* __restrict__ vec,
                           float* __restrict__ basis_pos, int* __restrict__ sndrow,
                           int* __restrict__ rcvrow)
{
    int e = blockIdx.x*256 + threadIdx.x;
    if (e >= N_EDGES) return;
    int r = inv[recv[e]];
    int q = row_ptr[r] + atomicAdd(&cursor[r], 1);
    sndrow[q] = pn[inv[senders[e]]];
    rcvrow[q] = pn[r];
    float x = vec[e*3+0], y = vec[e*3+1], z = vec[e*3+2];
    float rr = sqrtf(x*x + y*y + z*z);
    rr = fmaxf(rr, 1e-9f);
    float rc = fminf(rr, 5.0f);
    float cut = 0.5f * (cosf(PI_F * rc * 0.2f) + 1.f);
    float pref = sqrtf(0.4f) * cut / rr;
    float B[8];
    #pragma unroll
    for (int k = 1; k <= 8; ++k) B[k-1] = pref * sinf(PI_F * 0.2f * (float)k * rr);
    float4* dst = (float4*)(basis_pos + (size_t)q*8);
    dst[0] = make_float4(B[0], B[1], B[2], B[3]);
    dst[1] = make_float4(B[4], B[5], B[6], B[7]);
}

// ---- 6: fused radial MLP + aggregation for one layer: aggF[row][f] += scal*rw ----
// 2500 blocks x 64 positions; per-wave h/rw LDS overlay; phase-C gathers register-prefetched
__global__ __launch_bounds__(256) void k_rwagg(
    const int layer,
    const float* __restrict__ basis_pos,
    const float* __restrict__ rW1,
    const float* __restrict__ rb1,
    const ushort_t* __restrict__ W2T0,
    const int* __restrict__ sndrow,
    const int* __restrict__ rcvrow,
    const ushort_t* __restrict__ fB_in,
    float* __restrict__ aggF)
{
    __shared__ float W1s[NB*HR];            // 2 KB
    __shared__ float b1s[HR];               // 256 B
    __shared__ ushort_t buf[4][16*132];     // 16.9 KB per-wave overlay: h then rw
    __shared__ int sndS[64], rowS[64];

    const int t = threadIdx.x;
    const int wv = t >> 6;
    const int lane = t & 63;
    const int j64 = lane;
    const int r16 = lane & 15;
    const int quad = lane >> 4;
    const int p0b = blockIdx.x * 64;

    W1s[t] = rW1[layer*NB*HR + t];
    W1s[256 + t] = rW1[layer*NB*HR + 256 + t];
    if (t < HR) b1s[t] = rb1[layer*HR + t];
    if (t < 64) { sndS[t] = sndrow[p0b + t]; rowS[t] = rcvrow[p0b + t]; }
    __syncthreads();

    // phase A: h (bf16) for this wave's 16 positions, basis prefetched 4 edges ahead
    const int p0 = p0b + wv*16;
    {
        float4 pre[8];
        #pragma unroll
        for (int e = 0; e < 4; ++e) {
            const float4* B4 = (const float4*)(basis_pos + (size_t)(p0 + e)*8);
            pre[2*e] = B4[0]; pre[2*e+1] = B4[1];
        }
        #pragma unroll
        for (int eb = 0; eb < 4; ++eb) {
            float4 cur[8];
            #pragma unroll
            for (int j = 0; j < 8; ++j) cur[j] = pre[j];
            if (eb < 3) {
                #pragma unroll
                for (int e = 0; e < 4; ++e) {
                    const float4* B4 = (const float4*)(basis_pos + (size_t)(p0 + (eb+1)*4 + e)*8);
                    pre[2*e] = B4[0]; pre[2*e+1] = B4[1];
                }
            }
            #pragma unroll
            for (int e = 0; e < 4; ++e) {
                float4 x0 = cur[2*e], x1 = cur[2*e+1];
                float a = b1s[j64];
                a = fmaf(x0.x, W1s[0*HR + j64], a);
                a = fmaf(x0.y, W1s[1*HR + j64], a);
                a = fmaf(x0.z, W1s[2*HR + j64], a);
                a = fmaf(x0.w, W1s[3*HR + j64], a);
                a = fmaf(x1.x, W1s[4*HR + j64], a);
                a = fmaf(x1.y, W1s[5*HR + j64], a);
                a = fmaf(x1.z, W1s[6*HR + j64], a);
                a = fmaf(x1.w, W1s[7*HR + j64], a);
                buf[wv][(eb*4 + e)*132 + j64] = f2bf(a / (1.f + expf(-a)));
            }
        }
    }
    // phase B: load A-fragments (h dies here), MFMA, overwrite buf with rw
    {
        short8 a0 = *(const short8*)&buf[wv][r16*132 + quad*8];
        short8 a1 = *(const short8*)&buf[wv][r16*132 + 32 + quad*8];
        const ushort_t* W2l = W2T0 + layer*8192;
        #pragma unroll
        for (int nt = 0; nt < 8; ++nt) {
            const int col = nt*16 + r16;
            short8 b0 = *(const short8*)(W2l + (size_t)col*64 + quad*8);
            short8 b1 = *(const short8*)(W2l + (size_t)col*64 + 32 + quad*8);
            f32x4 c = (f32x4){0.f, 0.f, 0.f, 0.f};
            c = __builtin_amdgcn_mfma_f32_16x16x32_bf16(a0, b0, c, 0, 0, 0);
            c = __builtin_amdgcn_mfma_f32_16x16x32_bf16(a1, b1, c, 0, 0, 0);
            #pragma unroll
            for (int r = 0; r < 4; ++r)
                buf[wv][(quad*4 + r)*132 + col] = f2bf(c[r]);
        }
    }
    __syncthreads();

    // phase C: stage ALL 32 gathers into registers first (loads in flight together),
    // then run the run-length accumulate from registers + LDS.
    {
        const int f = t & 127, mh = t >> 7;
        const int base = mh*32;
        ushort_t sfv[32];
        #pragma unroll
        for (int i = 0; i < 32; ++i)
            sfv[i] = fB_in[(size_t)sndS[base + i]*128 + f];
        int cur = rowS[base];
        float acc = 0.f;
        #pragma unroll
        for (int i = 0; i < 32; ++i) {
            const int pl = base + i;
            const int row = rowS[pl];
            const float sf = bfu(sfv[i]);
            const float rl = bfu(buf[pl >> 4][(pl & 15)*132 + f]);
            if (row != cur) {
                atomicAdd(&aggF[(size_t)cur*128 + f], acc);
                cur = row; acc = 0.f;
            }
            acc = fmaf(sf, rl, acc);
        }
        atomicAdd(&aggF[(size_t)cur*128 + f], acc);
    }
}

// ---- tile -> species from psptr (10-step scan) ----
__device__ __forceinline__ int tile_to_spec(const int* __restrict__ psptr, int tile)
{
    int spec = 0;
    const int row = tile*16;
    #pragma unroll
    for (int s = 1; s < NSPEC; ++s)
        if (row >= psptr[s]) spec = s;
    return spec;
}

// ---- 7: layer-0 gemm+epi: lin GEMM + poly + fB1 + readout0; re-zeroes aggF tile ----
__global__ __launch_bounds__(256) void k_gemm_epi0(
    float* __restrict__ aggF,
    const ushort_t* __restrict__ WBlin0,
    const int* __restrict__ scnt, const int* __restrict__ sptr,
    const int* __restrict__ psptr, const int* __restrict__ perm,
    const float* __restrict__ prodc, const float* __restrict__ ro0,
    ushort_t* __restrict__ fB1, float* __restrict__ out)
{
    __shared__ float redS[16][65];
    const int tile = blockIdx.x;
    const int spec = tile_to_spec(psptr, tile);
    const int t = threadIdx.x;
    const int lane = t & 63;
    const int wv = t >> 6;
    const int r16 = lane & 15;
    const int quad = lane >> 4;

    float* Ap = aggF + (size_t)tile*2048;
    const ushort_t* Wp = WBlin0 + (size_t)spec*16384;
    const float* pc = prodc + (size_t)spec*3*F;

    short8 a[4];
    #pragma unroll
    for (int c = 0; c < 4; ++c)
        a[c] = pack8(Ap + (size_t)r16*128 + c*32 + quad*8);
    __syncthreads();   // all waves' reads done
    {   // zero tile for layer-1 atomic reuse
        f32x4 z = (f32x4){0.f, 0.f, 0.f, 0.f};
        *(f32x4*)(Ap + t*8) = z;
        *(f32x4*)(Ap + t*8 + 4) = z;
    }

    float pr[4] = {0.f, 0.f, 0.f, 0.f};
    #pragma unroll
    for (int nt = 0; nt < 2; ++nt) {
        const int col = wv*32 + nt*16 + r16;
        f32x4 acc = (f32x4){0.f, 0.f, 0.f, 0.f};
        #pragma unroll
        for (int c = 0; c < 4; ++c) {
            short8 b = *(const short8*)(Wp + (size_t)col*128 + c*32 + quad*8);
            acc = __builtin_amdgcn_mfma_f32_16x16x32_bf16(a[c], b, acc, 0, 0, 0);
        }
        const float w0 = ro0[col];
        const float p0c = pc[col], p1c = pc[F+col], p2c = pc[2*F+col];
        #pragma unroll
        for (int r = 0; r < 4; ++r) {
            float s = acc[r] * 0.5f;
            float val = s * (p0c + p1c*s + p2c*s*s);
            fB1[((size_t)tile*16 + quad*4 + r)*128 + col] = f2bf(val);
            pr[r] = fmaf(val, w0, pr[r]);
        }
    }
    #pragma unroll
    for (int r = 0; r < 4; ++r) redS[quad*4 + r][wv*16 + r16] = pr[r];
    __syncthreads();
    if (t < 16) {
        int rel = tile*16 + t - psptr[spec];
        if (rel >= 0 && rel < scnt[spec]) {
            float s = 0.f;
            for (int j = 0; j < 64; ++j) s += redS[t][j];
            out[(size_t)perm[sptr[spec] + rel]*2 + 0] = s;
        }
    }
}

// ---- 8: layer-1 gemm+epi: lin+sc GEMM + poly + MLP readout1 ----
__global__ __launch_bounds__(256) void k_gemm_epi1(
    const float* __restrict__ aggF,
    const ushort_t* __restrict__ fB1,
    const ushort_t* __restrict__ WBlin1, const ushort_t* __restrict__ WBsc0,
    const int* __restrict__ scnt, const int* __restrict__ sptr,
    const int* __restrict__ psptr, const int* __restrict__ perm,
    const float* __restrict__ prodc,
    const float* __restrict__ ro1W1, const float* __restrict__ ro1W2,
    float* __restrict__ out)
{
    __shared__ float sS[16][132];
    __shared__ float yS[16][17];
    const int tile = blockIdx.x;
    const int spec = tile_to_spec(psptr, tile);
    const int t = threadIdx.x;
    const int lane = t & 63;
    const int wv = t >> 6;
    const int r16 = lane & 15;
    const int quad = lane >> 4;

    const float* Ap = aggF + (size_t)tile*2048;
    const ushort_t* Fp = fB1 + (size_t)tile*16*128;
    const ushort_t* Wl = WBlin1 + (size_t)spec*16384;
    const ushort_t* Ws = WBsc0  + (size_t)spec*16384;
    const float* pc = prodc + ((size_t)NSPEC + spec)*3*F;

    short8 a1[4], a2[4];
    #pragma unroll
    for (int c = 0; c < 4; ++c) {
        a1[c] = pack8(Ap + (size_t)r16*128 + c*32 + quad*8);
        a2[c] = *(const short8*)(Fp + (size_t)r16*128 + c*32 + quad*8);
    }
    #pragma unroll
    for (int nt = 0; nt < 2; ++nt) {
        const int col = wv*32 + nt*16 + r16;
        f32x4 accl = (f32x4){0.f, 0.f, 0.f, 0.f};
        f32x4 accs = (f32x4){0.f, 0.f, 0.f, 0.f};
        #pragma unroll
        for (int c = 0; c < 4; ++c) {
            short8 bl = *(const short8*)(Wl + (size_t)col*128 + c*32 + quad*8);
            short8 bs = *(const short8*)(Ws + (size_t)col*128 + c*32 + quad*8);
            accl = __builtin_amdgcn_mfma_f32_16x16x32_bf16(a1[c], bl, accl, 0, 0, 0);
            accs = __builtin_amdgcn_mfma_f32_16x16x32_bf16(a2[c], bs, accs, 0, 0, 0);
        }
        const float p0c = pc[col], p1c = pc[F+col], p2c = pc[2*F+col];
        #pragma unroll
        for (int r = 0; r < 4; ++r) {
            float s = accl[r] * 0.5f;
            sS[quad*4 + r][col] = s * (p0c + p1c*s + p2c*s*s) + accs[r];
        }
    }
    __syncthreads();
    {
        const int node = t >> 4, c = t & 15;
        float a = 0.f;
        #pragma unroll 8
        for (int g = 0; g < F; ++g) a = fmaf(sS[node][g], ro1W1[g*16 + c], a);
        a = silu_f(a);
        yS[node][c] = a * ro1W2[c];
    }
    __syncthreads();
    if (t < 16) {
        int rel = tile*16 + t - psptr[spec];
        if (rel >= 0 && rel < scnt[spec]) {
            float s = 0.f;
            #pragma unroll
            for (int j = 0; j < 16; ++j) s += yS[t][j];
            out[(size_t)perm[sptr[spec] + rel]*2 + 1] = s;
        }
    }
}

extern "C" void kernel_launch(void* const* d_in, const int* in_sizes, int n_in,
                              void* d_out, int out_size, void* d_ws, size_t ws_size,
                              hipStream_t stream)
{
    (void)in_sizes; (void)n_in; (void)out_size; (void)ws_size;
    const float* vectors   = (const float*)d_in[0];
    const int*   spec      = (const int*)d_in[1];
    const int*   senders   = (const int*)d_in[2];
    const int*   receivers = (const int*)d_in[3];
    const float* embW      = (const float*)d_in[4];
    const float* rW1       = (const float*)d_in[5];
    const float* rb1       = (const float*)d_in[6];
    const float* rW2       = (const float*)d_in[7];
    const float* linW      = (const float*)d_in[8];
    const float* prodc     = (const float*)d_in[9];
    const float* scW       = (const float*)d_in[10];
    const float* ro0       = (const float*)d_in[11];
    const float* ro1W1     = (const float*)d_in[12];
    const float* ro1W2     = (const float*)d_in[13];
    float* out = (float*)d_out;

    char* ws = (char*)d_ws;
    float*    basis_pos = (float*)ws;    ws += sizeof(float)*(size_t)N_EDGES*8;
    float*    aggF      = (float*)ws;    ws += sizeof(float)*(size_t)NPAD*128;
    ushort_t* fB0       = (ushort_t*)ws; ws += sizeof(ushort_t)*(size_t)NPAD*128;
    ushort_t* fB1       = (ushort_t*)ws; ws += sizeof(ushort_t)*(size_t)NPAD*128;
    ushort_t* WBlin0    = (ushort_t*)ws; ws += sizeof(ushort_t)*(size_t)2*NSPEC*16384;
    ushort_t* WBsc0     = (ushort_t*)ws; ws += sizeof(ushort_t)*(size_t)NSPEC*16384;
    ushort_t* W2T0      = (ushort_t*)ws; ws += sizeof(ushort_t)*(size_t)2*128*64;
    int* sndrow    = (int*)ws; ws += sizeof(int)*N_EDGES;
    int* rcvrow    = (int*)ws; ws += sizeof(int)*N_EDGES;
    int* row_ptr   = (int*)ws; ws += sizeof(int)*(N_NODES+1);
    int* counts    = (int*)ws; ws += sizeof(int)*N_NODES;   // zero region start
    int* cursor    = (int*)ws; ws += sizeof(int)*N_NODES;
    int* scnt      = (int*)ws; ws += sizeof(int)*16;
    int* scur      = (int*)ws; ws += sizeof(int)*16;
    int* sptr      = (int*)ws; ws += sizeof(int)*16;
    int* psptr     = (int*)ws; ws += sizeof(int)*16;
    int* perm      = (int*)ws; ws += sizeof(int)*N_NODES;
    int* inv       = (int*)ws; ws += sizeof(int)*N_NODES;
    int* specS     = (int*)ws; ws += sizeof(int)*N_NODES;
    int* pn        = (int*)ws; ws += sizeof(int)*N_NODES;

    const int EB = (N_EDGES + 255)/256;

    k_conv_zero<<<1984, 256, 0, stream>>>(linW, scW, rW2, WBlin0, WBsc0, W2T0, counts, aggF);
    k_hist<<<EB, 256, 0, stream>>>(spec, receivers, scnt, counts);
    k_sfill<<<(N_NODES + 255)/256, 256, 0, stream>>>(spec, scnt, sptr, psptr, scur,
                                                     perm, inv, specS, pn);
    k_scan_init<<<1 + (N_NODES*F + 255)/256, 256, 0, stream>>>(counts, perm, row_ptr,
                                                               specS, pn, embW, fB0);
    k_fill_pre<<<EB, 256, 0, stream>>>(receivers, senders, inv, pn, row_ptr, cursor,
                                       vectors, basis_pos, sndrow, rcvrow);

    // layer 0
    k_rwagg<<<ETILES, 256, 0, stream>>>(0, basis_pos, rW1, rb1, W2T0,
                                        sndrow, rcvrow, fB0, aggF);
    k_gemm_epi0<<<NT_MAX, 256, 0, stream>>>(aggF, WBlin0, scnt, sptr, psptr, perm,
                                            prodc, ro0, fB1, out);
    // layer 1
    k_rwagg<<<ETILES, 256, 0, stream>>>(1, basis_pos, rW1, rb1, W2T0,
                                        sndrow, rcvrow, fB1, aggF);
    k_gemm_epi1<<<NT_MAX, 256, 0, stream>>>(aggF, fB1, WBlin0 + (size_t)NSPEC*16384, WBsc0,
                                            scnt, sptr, psptr, perm, prodc, ro1W1, ro1W2, out);
}

// Round 22
// 270.902 us; speedup vs baseline: 1.1714x; 1.0846x over previous
//
#include <hip/hip_runtime.h>
#include <math.h>
#include <stdint.h>

#define N_NODES 10000
#define N_EDGES 160000
#define F 128
#define NB 8
#define HR 64
#define NSPEC 10
#define PI_F 3.14159265358979323846f
#define NPAD 10160
#define NT_MAX 635
#define ETILES 2500

typedef unsigned short ushort_t;
typedef __attribute__((ext_vector_type(8))) short short8;
typedef __attribute__((ext_vector_type(4))) float f32x4;

__device__ __forceinline__ float silu_f(float x){ return x / (1.f + expf(-x)); }
__device__ __forceinline__ float bfu(ushort_t u) {
    union { unsigned int i; float f; } v; v.i = ((unsigned int)u) << 16; return v.f;
}
__device__ __forceinline__ ushort_t f2bf(float f) {
    union { float f; unsigned int i; } v; v.f = f;
    unsigned int x = v.i;
    unsigned int r = (x + 0x7fffu + ((x >> 16) & 1u)) >> 16;
    return (ushort_t)r;
}
__device__ __forceinline__ short8 pack8(const float* p) {
    short8 r;
    #pragma unroll
    for (int i = 0; i < 8; ++i) r[i] = (short)f2bf(p[i]);
    return r;
}

// ---- 1: zero counters + aggF + convert weights ----
__global__ __launch_bounds__(256) void k_conv_zero(
    const float* __restrict__ linW, const float* __restrict__ scW, const float* __restrict__ rW2,
    ushort_t* __restrict__ WBlin0, ushort_t* __restrict__ WBsc0, ushort_t* __restrict__ W2T0,
    int* __restrict__ zero_base, float* __restrict__ aggF)
{
    const int gtid = blockIdx.x*256 + threadIdx.x;
    const int GRID = 1984*256;
    for (int i = gtid; i < 2*N_NODES + 32; i += GRID) zero_base[i] = 0;
    for (int i = gtid; i < NPAD*128; i += GRID) aggF[i] = 0.f;
    const int LINTOT = 2*NSPEC*16384;
    const int SCTOT  = NSPEC*16384;
    int i = gtid;
    if (i < LINTOT) {
        int mat = i >> 14;
        int r = i & 16383;
        int fo = r >> 7, fi = r & 127;
        WBlin0[(size_t)mat*16384 + fo*128 + fi] =
            f2bf(linW[((size_t)mat*4 + 0)*16384 + fi*128 + fo]);
    } else if (i < LINTOT + SCTOT) {
        int t2 = i - LINTOT;
        int sp = t2 >> 14;
        int r = t2 & 16383;
        int fo = r >> 7, fi = r & 127;
        WBsc0[(size_t)sp*16384 + fo*128 + fi] =
            f2bf(scW[((size_t)(NSPEC + sp)*4 + 0)*16384 + fi*128 + fo]);
    } else if (i < LINTOT + SCTOT + 2*128*64) {
        int t2 = i - LINTOT - SCTOT;
        int l = t2 >> 13; int r = t2 & 8191; int f = r >> 6; int k = r & 63;
        W2T0[t2] = f2bf(rW2[(size_t)l*HR*512 + (size_t)k*512 + 4*f]);
    }
}

// ---- 2: both histograms; scnt via per-block LDS histogram (10-address contention fix) ----
__global__ __launch_bounds__(256) void k_hist(
    const int* __restrict__ spec, const int* __restrict__ recv,
    int* __restrict__ scnt, int* __restrict__ counts)
{
    __shared__ int h[NSPEC];
    const int t = threadIdx.x;
    if (t < NSPEC) h[t] = 0;
    __syncthreads();
    int i = blockIdx.x*256 + t;
    if (i < N_EDGES) atomicAdd(&counts[recv[i]], 1);
    if (i < N_NODES) atomicAdd(&h[spec[i]], 1);
    __syncthreads();
    if (t < NSPEC && h[t] > 0) atomicAdd(&scnt[t], h[t]);
}

// ---- 3: sort fill with per-block local species scan; block 0 publishes sptr/psptr ----
__global__ __launch_bounds__(256) void k_sfill(
    const int* __restrict__ spec, const int* __restrict__ scnt,
    int* __restrict__ sptr, int* __restrict__ psptr,
    int* __restrict__ scur, int* __restrict__ perm,
    int* __restrict__ inv, int* __restrict__ specS, int* __restrict__ pn)
{
    __shared__ int sptrL[NSPEC+1], psptrL[NSPEC+1];
    const int t = threadIdx.x;
    if (t == 0) {
        int acc = 0, pacc = 0;
        for (int s = 0; s < NSPEC; ++s) {
            sptrL[s] = acc; psptrL[s] = pacc;
            acc += scnt[s];
            pacc += ((scnt[s] + 15) >> 4) << 4;
        }
        sptrL[NSPEC] = acc; psptrL[NSPEC] = pacc;
        if (blockIdx.x == 0) {
            for (int s = 0; s <= NSPEC; ++s) { sptr[s] = sptrL[s]; psptr[s] = psptrL[s]; }
        }
    }
    __syncthreads();
    int n = blockIdx.x*256 + t;
    if (n >= N_NODES) return;
    int s = spec[n];
    int pos = sptrL[s] + atomicAdd(&scur[s], 1);
    perm[pos] = n; inv[n] = pos; specS[pos] = s;
    pn[pos] = psptrL[s] + (pos - sptrL[s]);
}

// ---- 4: row_ptr scan (block 0) + fB0 init (other blocks) ----
__global__ __launch_bounds__(256) void k_scan_init(
    const int* __restrict__ counts, const int* __restrict__ perm, int* __restrict__ row_ptr,
    const int* __restrict__ specS, const int* __restrict__ pn,
    const float* __restrict__ embW, ushort_t* __restrict__ fB0)
{
    const int t = threadIdx.x;
    if (blockIdx.x == 0) {
        __shared__ int ps[256];
        int loc[40];
        int sum = 0;
        int base = t * 40;
        #pragma unroll
        for (int j = 0; j < 40; ++j) {
            int idx = base + j;
            int c = (idx < N_NODES) ? counts[perm[idx]] : 0;
            loc[j] = c; sum += c;
        }
        ps[t] = sum;
        __syncthreads();
        for (int off = 1; off < 256; off <<= 1) {
            int v = (t >= off) ? ps[t-off] : 0;
            __syncthreads();
            ps[t] += v;
            __syncthreads();
        }
        int ex = ps[t] - sum;
        #pragma unroll
        for (int j = 0; j < 40; ++j) {
            int idx = base + j;
            if (idx < N_NODES) row_ptr[idx] = ex;
            ex += loc[j];
        }
        if (t == 255) row_ptr[N_NODES] = ex;
    } else {
        int i = (blockIdx.x - 1)*256 + t;
        if (i < N_NODES*F) {
            int n = i >> 7, f = i & 127;
            fB0[(size_t)pn[n]*128 + f] = f2bf(embW[specS[n]*F + f]);
        }
    }
}

// ---- 5: CSR fill + basis + sender/receiver rows ----
__global__ void k_fill_pre(const int* __restrict__ recv, const int* __restrict__ senders,
                           const int* __restrict__ inv, const int* __restrict__ pn,
                           const int* __restrict__ row_ptr, int* __restrict__ cursor,
                           const float* __restrict__ vec,
                           float* __restrict__ basis_pos, int* __restrict__ sndrow,
                           int* __restrict__ rcvrow)
{
    int e = blockIdx.x*256 + threadIdx.x;
    if (e >= N_EDGES) return;
    int r = inv[recv[e]];
    int q = row_ptr[r] + atomicAdd(&cursor[r], 1);
    sndrow[q] = pn[inv[senders[e]]];
    rcvrow[q] = pn[r];
    float x = vec[e*3+0], y = vec[e*3+1], z = vec[e*3+2];
    float rr = sqrtf(x*x + y*y + z*z);
    rr = fmaxf(rr, 1e-9f);
    float rc = fminf(rr, 5.0f);
    float cut = 0.5f * (cosf(PI_F * rc * 0.2f) + 1.f);
    float pref = sqrtf(0.4f) * cut / rr;
    float B[8];
    #pragma unroll
    for (int k = 1; k <= 8; ++k) B[k-1] = pref * sinf(PI_F * 0.2f * (float)k * rr);
    float4* dst = (float4*)(basis_pos + (size_t)q*8);
    dst[0] = make_float4(B[0], B[1], B[2], B[3]);
    dst[1] = make_float4(B[4], B[5], B[6], B[7]);
}

// ---- 6: fused radial MLP + aggregation for one layer: aggF[row][f] += scal*rw ----
// 2500 blocks x 64 positions; per-wave h/rw LDS overlay; phase-C gathers register-prefetched
__global__ __launch_bounds__(256) void k_rwagg(
    const int layer,
    const float* __restrict__ basis_pos,
    const float* __restrict__ rW1,
    const float* __restrict__ rb1,
    const ushort_t* __restrict__ W2T0,
    const int* __restrict__ sndrow,
    const int* __restrict__ rcvrow,
    const ushort_t* __restrict__ fB_in,
    float* __restrict__ aggF)
{
    __shared__ float W1s[NB*HR];            // 2 KB
    __shared__ float b1s[HR];               // 256 B
    __shared__ ushort_t buf[4][16*132];     // 16.9 KB per-wave overlay: h then rw
    __shared__ int sndS[64], rowS[64];

    const int t = threadIdx.x;
    const int wv = t >> 6;
    const int lane = t & 63;
    const int j64 = lane;
    const int r16 = lane & 15;
    const int quad = lane >> 4;
    const int p0b = blockIdx.x * 64;

    W1s[t] = rW1[layer*NB*HR + t];
    W1s[256 + t] = rW1[layer*NB*HR + 256 + t];
    if (t < HR) b1s[t] = rb1[layer*HR + t];
    if (t < 64) { sndS[t] = sndrow[p0b + t]; rowS[t] = rcvrow[p0b + t]; }
    __syncthreads();

    // phase A: h (bf16) for this wave's 16 positions, basis prefetched 4 edges ahead
    const int p0 = p0b + wv*16;
    {
        float4 pre[8];
        #pragma unroll
        for (int e = 0; e < 4; ++e) {
            const float4* B4 = (const float4*)(basis_pos + (size_t)(p0 + e)*8);
            pre[2*e] = B4[0]; pre[2*e+1] = B4[1];
        }
        #pragma unroll
        for (int eb = 0; eb < 4; ++eb) {
            float4 cur[8];
            #pragma unroll
            for (int j = 0; j < 8; ++j) cur[j] = pre[j];
            if (eb < 3) {
                #pragma unroll
                for (int e = 0; e < 4; ++e) {
                    const float4* B4 = (const float4*)(basis_pos + (size_t)(p0 + (eb+1)*4 + e)*8);
                    pre[2*e] = B4[0]; pre[2*e+1] = B4[1];
                }
            }
            #pragma unroll
            for (int e = 0; e < 4; ++e) {
                float4 x0 = cur[2*e], x1 = cur[2*e+1];
                float a = b1s[j64];
                a = fmaf(x0.x, W1s[0*HR + j64], a);
                a = fmaf(x0.y, W1s[1*HR + j64], a);
                a = fmaf(x0.z, W1s[2*HR + j64], a);
                a = fmaf(x0.w, W1s[3*HR + j64], a);
                a = fmaf(x1.x, W1s[4*HR + j64], a);
                a = fmaf(x1.y, W1s[5*HR + j64], a);
                a = fmaf(x1.z, W1s[6*HR + j64], a);
                a = fmaf(x1.w, W1s[7*HR + j64], a);
                buf[wv][(eb*4 + e)*132 + j64] = f2bf(a / (1.f + expf(-a)));
            }
        }
    }
    // phase B: load A-fragments (h dies here), MFMA, overwrite buf with rw
    {
        short8 a0 = *(const short8*)&buf[wv][r16*132 + quad*8];
        short8 a1 = *(const short8*)&buf[wv][r16*132 + 32 + quad*8];
        const ushort_t* W2l = W2T0 + layer*8192;
        #pragma unroll
        for (int nt = 0; nt < 8; ++nt) {
            const int col = nt*16 + r16;
            short8 b0 = *(const short8*)(W2l + (size_t)col*64 + quad*8);
            short8 b1 = *(const short8*)(W2l + (size_t)col*64 + 32 + quad*8);
            f32x4 c = (f32x4){0.f, 0.f, 0.f, 0.f};
            c = __builtin_amdgcn_mfma_f32_16x16x32_bf16(a0, b0, c, 0, 0, 0);
            c = __builtin_amdgcn_mfma_f32_16x16x32_bf16(a1, b1, c, 0, 0, 0);
            #pragma unroll
            for (int r = 0; r < 4; ++r)
                buf[wv][(quad*4 + r)*132 + col] = f2bf(c[r]);
        }
    }
    __syncthreads();

    // phase C: stage ALL 32 gathers into registers first (loads in flight together),
    // then run the run-length accumulate from registers + LDS.
    {
        const int f = t & 127, mh = t >> 7;
        const int base = mh*32;
        ushort_t sfv[32];
        #pragma unroll
        for (int i = 0; i < 32; ++i)
            sfv[i] = fB_in[(size_t)sndS[base + i]*128 + f];
        int cur = rowS[base];
        float acc = 0.f;
        #pragma unroll
        for (int i = 0; i < 32; ++i) {
            const int pl = base + i;
            const int row = rowS[pl];
            const float sf = bfu(sfv[i]);
            const float rl = bfu(buf[pl >> 4][(pl & 15)*132 + f]);
            if (row != cur) {
                atomicAdd(&aggF[(size_t)cur*128 + f], acc);
                cur = row; acc = 0.f;
            }
            acc = fmaf(sf, rl, acc);
        }
        atomicAdd(&aggF[(size_t)cur*128 + f], acc);
    }
}

// ---- tile -> species from psptr (10-step scan) ----
__device__ __forceinline__ int tile_to_spec(const int* __restrict__ psptr, int tile)
{
    int spec = 0;
    const int row = tile*16;
    #pragma unroll
    for (int s = 1; s < NSPEC; ++s)
        if (row >= psptr[s]) spec = s;
    return spec;
}

// ---- 7: layer-0 gemm+epi: lin GEMM + poly + fB1 + readout0; re-zeroes aggF tile ----
__global__ __launch_bounds__(256) void k_gemm_epi0(
    float* __restrict__ aggF,
    const ushort_t* __restrict__ WBlin0,
    const int* __restrict__ scnt, const int* __restrict__ sptr,
    const int* __restrict__ psptr, const int* __restrict__ perm,
    const float* __restrict__ prodc, const float* __restrict__ ro0,
    ushort_t* __restrict__ fB1, float* __restrict__ out)
{
    __shared__ float redS[16][65];
    const int tile = blockIdx.x;
    const int spec = tile_to_spec(psptr, tile);
    const int t = threadIdx.x;
    const int lane = t & 63;
    const int wv = t >> 6;
    const int r16 = lane & 15;
    const int quad = lane >> 4;

    float* Ap = aggF + (size_t)tile*2048;
    const ushort_t* Wp = WBlin0 + (size_t)spec*16384;
    const float* pc = prodc + (size_t)spec*3*F;

    short8 a[4];
    #pragma unroll
    for (int c = 0; c < 4; ++c)
        a[c] = pack8(Ap + (size_t)r16*128 + c*32 + quad*8);
    __syncthreads();   // all waves' reads done
    {   // zero tile for layer-1 atomic reuse
        f32x4 z = (f32x4){0.f, 0.f, 0.f, 0.f};
        *(f32x4*)(Ap + t*8) = z;
        *(f32x4*)(Ap + t*8 + 4) = z;
    }

    float pr[4] = {0.f, 0.f, 0.f, 0.f};
    #pragma unroll
    for (int nt = 0; nt < 2; ++nt) {
        const int col = wv*32 + nt*16 + r16;
        f32x4 acc = (f32x4){0.f, 0.f, 0.f, 0.f};
        #pragma unroll
        for (int c = 0; c < 4; ++c) {
            short8 b = *(const short8*)(Wp + (size_t)col*128 + c*32 + quad*8);
            acc = __builtin_amdgcn_mfma_f32_16x16x32_bf16(a[c], b, acc, 0, 0, 0);
        }
        const float w0 = ro0[col];
        const float p0c = pc[col], p1c = pc[F+col], p2c = pc[2*F+col];
        #pragma unroll
        for (int r = 0; r < 4; ++r) {
            float s = acc[r] * 0.5f;
            float val = s * (p0c + p1c*s + p2c*s*s);
            fB1[((size_t)tile*16 + quad*4 + r)*128 + col] = f2bf(val);
            pr[r] = fmaf(val, w0, pr[r]);
        }
    }
    #pragma unroll
    for (int r = 0; r < 4; ++r) redS[quad*4 + r][wv*16 + r16] = pr[r];
    __syncthreads();
    if (t < 16) {
        int rel = tile*16 + t - psptr[spec];
        if (rel >= 0 && rel < scnt[spec]) {
            float s = 0.f;
            for (int j = 0; j < 64; ++j) s += redS[t][j];
            out[(size_t)perm[sptr[spec] + rel]*2 + 0] = s;
        }
    }
}

// ---- 8: layer-1 gemm+epi: lin+sc GEMM + poly + MLP readout1 ----
__global__ __launch_bounds__(256) void k_gemm_epi1(
    const float* __restrict__ aggF,
    const ushort_t* __restrict__ fB1,
    const ushort_t* __restrict__ WBlin1, const ushort_t* __restrict__ WBsc0,
    const int* __restrict__ scnt, const int* __restrict__ sptr,
    const int* __restrict__ psptr, const int* __restrict__ perm,
    const float* __restrict__ prodc,
    const float* __restrict__ ro1W1, const float* __restrict__ ro1W2,
    float* __restrict__ out)
{
    __shared__ float sS[16][132];
    __shared__ float yS[16][17];
    const int tile = blockIdx.x;
    const int spec = tile_to_spec(psptr, tile);
    const int t = threadIdx.x;
    const int lane = t & 63;
    const int wv = t >> 6;
    const int r16 = lane & 15;
    const int quad = lane >> 4;

    const float* Ap = aggF + (size_t)tile*2048;
    const ushort_t* Fp = fB1 + (size_t)tile*16*128;
    const ushort_t* Wl = WBlin1 + (size_t)spec*16384;
    const ushort_t* Ws = WBsc0  + (size_t)spec*16384;
    const float* pc = prodc + ((size_t)NSPEC + spec)*3*F;

    short8 a1[4], a2[4];
    #pragma unroll
    for (int c = 0; c < 4; ++c) {
        a1[c] = pack8(Ap + (size_t)r16*128 + c*32 + quad*8);
        a2[c] = *(const short8*)(Fp + (size_t)r16*128 + c*32 + quad*8);
    }
    #pragma unroll
    for (int nt = 0; nt < 2; ++nt) {
        const int col = wv*32 + nt*16 + r16;
        f32x4 accl = (f32x4){0.f, 0.f, 0.f, 0.f};
        f32x4 accs = (f32x4){0.f, 0.f, 0.f, 0.f};
        #pragma unroll
        for (int c = 0; c < 4; ++c) {
            short8 bl = *(const short8*)(Wl + (size_t)col*128 + c*32 + quad*8);
            short8 bs = *(const short8*)(Ws + (size_t)col*128 + c*32 + quad*8);
            accl = __builtin_amdgcn_mfma_f32_16x16x32_bf16(a1[c], bl, accl, 0, 0, 0);
            accs = __builtin_amdgcn_mfma_f32_16x16x32_bf16(a2[c], bs, accs, 0, 0, 0);
        }
        const float p0c = pc[col], p1c = pc[F+col], p2c = pc[2*F+col];
        #pragma unroll
        for (int r = 0; r < 4; ++r) {
            float s = accl[r] * 0.5f;
            sS[quad*4 + r][col] = s * (p0c + p1c*s + p2c*s*s) + accs[r];
        }
    }
    __syncthreads();
    {
        const int node = t >> 4, c = t & 15;
        float a = 0.f;
        #pragma unroll 8
        for (int g = 0; g < F; ++g) a = fmaf(sS[node][g], ro1W1[g*16 + c], a);
        a = silu_f(a);
        yS[node][c] = a * ro1W2[c];
    }
    __syncthreads();
    if (t < 16) {
        int rel = tile*16 + t - psptr[spec];
        if (rel >= 0 && rel < scnt[spec]) {
            float s = 0.f;
            #pragma unroll
            for (int j = 0; j < 16; ++j) s += yS[t][j];
            out[(size_t)perm[sptr[spec] + rel]*2 + 1] = s;
        }
    }
}

extern "C" void kernel_launch(void* const* d_in, const int* in_sizes, int n_in,
                              void* d_out, int out_size, void* d_ws, size_t ws_size,
                              hipStream_t stream)
{
    (void)in_sizes; (void)n_in; (void)out_size; (void)ws_size;
    const float* vectors   = (const float*)d_in[0];
    const int*   spec      = (const int*)d_in[1];
    const int*   senders   = (const int*)d_in[2];
    const int*   receivers = (const int*)d_in[3];
    const float* embW      = (const float*)d_in[4];
    const float* rW1       = (const float*)d_in[5];
    const float* rb1       = (const float*)d_in[6];
    const float* rW2       = (const float*)d_in[7];
    const float* linW      = (const float*)d_in[8];
    const float* prodc     = (const float*)d_in[9];
    const float* scW       = (const float*)d_in[10];
    const float* ro0       = (const float*)d_in[11];
    const float* ro1W1     = (const float*)d_in[12];
    const float* ro1W2     = (const float*)d_in[13];
    float* out = (float*)d_out;

    char* ws = (char*)d_ws;
    float*    basis_pos = (float*)ws;    ws += sizeof(float)*(size_t)N_EDGES*8;
    float*    aggF      = (float*)ws;    ws += sizeof(float)*(size_t)NPAD*128;
    ushort_t* fB0       = (ushort_t*)ws; ws += sizeof(ushort_t)*(size_t)NPAD*128;
    ushort_t* fB1       = (ushort_t*)ws; ws += sizeof(ushort_t)*(size_t)NPAD*128;
    ushort_t* WBlin0    = (ushort_t*)ws; ws += sizeof(ushort_t)*(size_t)2*NSPEC*16384;
    ushort_t* WBsc0     = (ushort_t*)ws; ws += sizeof(ushort_t)*(size_t)NSPEC*16384;
    ushort_t* W2T0      = (ushort_t*)ws; ws += sizeof(ushort_t)*(size_t)2*128*64;
    int* sndrow    = (int*)ws; ws += sizeof(int)*N_EDGES;
    int* rcvrow    = (int*)ws; ws += sizeof(int)*N_EDGES;
    int* row_ptr   = (int*)ws; ws += sizeof(int)*(N_NODES+1);
    int* counts    = (int*)ws; ws += sizeof(int)*N_NODES;   // zero region start
    int* cursor    = (int*)ws; ws += sizeof(int)*N_NODES;
    int* scnt      = (int*)ws; ws += sizeof(int)*16;
    int* scur      = (int*)ws; ws += sizeof(int)*16;
    int* sptr      = (int*)ws; ws += sizeof(int)*16;
    int* psptr     = (int*)ws; ws += sizeof(int)*16;
    int* perm      = (int*)ws; ws += sizeof(int)*N_NODES;
    int* inv       = (int*)ws; ws += sizeof(int)*N_NODES;
    int* specS     = (int*)ws; ws += sizeof(int)*N_NODES;
    int* pn        = (int*)ws; ws += sizeof(int)*N_NODES;

    const int EB = (N_EDGES + 255)/256;

    k_conv_zero<<<1984, 256, 0, stream>>>(linW, scW, rW2, WBlin0, WBsc0, W2T0, counts, aggF);
    k_hist<<<EB, 256, 0, stream>>>(spec, receivers, scnt, counts);
    k_sfill<<<(N_NODES + 255)/256, 256, 0, stream>>>(spec, scnt, sptr, psptr, scur,
                                                     perm, inv, specS, pn);
    k_scan_init<<<1 + (N_NODES*F + 255)/256, 256, 0, stream>>>(counts, perm, row_ptr,
                                                               specS, pn, embW, fB0);
    k_fill_pre<<<EB, 256, 0, stream>>>(receivers, senders, inv, pn, row_ptr, cursor,
                                       vectors, basis_pos, sndrow, rcvrow);

    // layer 0
    k_rwagg<<<ETILES, 256, 0, stream>>>(0, basis_pos, rW1, rb1, W2T0,
                                        sndrow, rcvrow, fB0, aggF);
    k_gemm_epi0<<<NT_MAX, 256, 0, stream>>>(aggF, WBlin0, scnt, sptr, psptr, perm,
                                            prodc, ro0, fB1, out);
    // layer 1
    k_rwagg<<<ETILES, 256, 0, stream>>>(1, basis_pos, rW1, rb1, W2T0,
                                        sndrow, rcvrow, fB1, aggF);
    k_gemm_epi1<<<NT_MAX, 256, 0, stream>>>(aggF, fB1, WBlin0 + (size_t)NSPEC*16384, WBsc0,
                                            scnt, sptr, psptr, perm, prodc, ro1W1, ro1W2, out);
}